// Round 1
// baseline (1059.167 us; speedup 1.0000x reference)
//
#include <hip/hip_runtime.h>

typedef __attribute__((ext_vector_type(8))) short bf16x8;
typedef __attribute__((ext_vector_type(4))) float f32x4;

#define LDS_STRIDE 136
#define INV_TEMP 0.08838834764831845f   // 1/sqrt(128)

static __device__ __forceinline__ unsigned short f2b(float f) {
    union { float f; unsigned int u; } v; v.f = f;
    unsigned int b = (v.u + 0x7fffu + ((v.u >> 16) & 1u)) >> 16;
    return (unsigned short)b;
}
static __device__ __forceinline__ float b2f(unsigned short s) {
    union { float f; unsigned int u; } v; v.u = ((unsigned int)s) << 16;
    return v.f;
}

// Convert the four 128x128 fp32 weights to bf16 row-major in workspace.
__global__ void prep_weights(const float* __restrict__ Wq, const float* __restrict__ Wk,
                             const float* __restrict__ Wv, const float* __restrict__ Wo,
                             unsigned short* __restrict__ wbf) {
    int i = blockIdx.x * 256 + threadIdx.x;       // 64 blocks x 256 = 16384
    wbf[i]          = f2b(Wq[i]);
    wbf[16384 + i]  = f2b(Wk[i]);
    wbf[32768 + i]  = f2b(Wv[i]);
    wbf[49152 + i]  = f2b(Wo[i]);
}

__launch_bounds__(512, 2)
__global__ void patch_attn(const float* __restrict__ x,
                           const float* __restrict__ bq, const float* __restrict__ bk,
                           const float* __restrict__ bv, const float* __restrict__ bo,
                           const unsigned short* __restrict__ wbf,
                           float* __restrict__ out)
{
    __shared__ __align__(16) unsigned short sPT[256 * LDS_STRIDE];  // 69,632 B, persistent
    __shared__ __align__(16) unsigned char  sUN[72704];             // time-multiplexed union

    const int tid  = threadIdx.x;
    const int w    = tid >> 6;
    const int lane = tid & 63;
    const int quad = lane >> 4;
    const int l16  = lane & 15;

    const int pid = blockIdx.x;            // 2048 patches
    const int b   = pid >> 10;
    const int n   = pid & 1023;
    const int gy  = n >> 5, gx = n & 31;
    const long patch_off = ((long)(b * 128) * 512 + gy * 16) * 512 + gx * 16;

    const unsigned short* Wq_bf = wbf;
    const unsigned short* Wk_bf = wbf + 16384;
    const unsigned short* Wv_bf = wbf + 32768;
    const unsigned short* Wo_bf = wbf + 49152;

    // ---------------- Phase 0: stage patch token-major (bf16) ----------------
    for (int i = tid; i < 8192; i += 512) {
        int c = i >> 6, rem = i & 63, sh = rem >> 2, sw4 = (rem & 3) * 4;
        const float4 f = *(const float4*)(x + patch_off + ((long)c * 512 + sh) * 512 + sw4);
        int l = sh * 16 + sw4;
        sPT[(l + 0) * LDS_STRIDE + c] = f2b(f.x);
        sPT[(l + 1) * LDS_STRIDE + c] = f2b(f.y);
        sPT[(l + 2) * LDS_STRIDE + c] = f2b(f.z);
        sPT[(l + 3) * LDS_STRIDE + c] = f2b(f.w);
    }
    __syncthreads();

    // ---------------- Phase 1: q-projection -> registers (A-frag form) -------
    // D[l,d] = pT(A) x Wq_rm(B); epilogue: +bq, * INV_TEMP; round-trip LDS.
    unsigned short* qscr = (unsigned short*)sUN + w * (32 * LDS_STRIDE); // per-wave 8,704 B
    const int lbase = w * 32;

    for (int lt = 0; lt < 2; ++lt) {
        int l0 = lbase + lt * 16;
        bf16x8 a[4];
#pragma unroll
        for (int ks = 0; ks < 4; ++ks)
            a[ks] = *(const bf16x8*)&sPT[(l0 + l16) * LDS_STRIDE + ks * 32 + quad * 8];
#pragma unroll
        for (int dt = 0; dt < 8; ++dt) {
            f32x4 acc = {0.f, 0.f, 0.f, 0.f};
#pragma unroll
            for (int ks = 0; ks < 4; ++ks) {
                bf16x8 bb = *(const bf16x8*)(Wq_bf + (dt * 16 + l16) * 128 + ks * 32 + quad * 8);
                acc = __builtin_amdgcn_mfma_f32_16x16x32_bf16(a[ks], bb, acc, 0, 0, 0);
            }
            int d = dt * 16 + l16;
            float bias = bq[d];
#pragma unroll
            for (int r = 0; r < 4; ++r)
                qscr[(lt * 16 + quad * 4 + r) * LDS_STRIDE + d] = f2b((acc[r] + bias) * INV_TEMP);
        }
    }
    // read back q as A-fragments (wave-private scratch; compiler orders LDS deps)
    bf16x8 qfrag[2][4];
#pragma unroll
    for (int lt = 0; lt < 2; ++lt)
#pragma unroll
        for (int ks = 0; ks < 4; ++ks)
            qfrag[lt][ks] = *(const bf16x8*)&qscr[(lt * 16 + l16) * LDS_STRIDE + ks * 32 + quad * 8];
    __syncthreads();   // release union region for the flash loop

    // ---------------- Phase 2: flash over 4 key-chunks of 64 -----------------
    unsigned short* kTc = (unsigned short*)sUN;                       // [64][136]
    unsigned short* vTc = (unsigned short*)(sUN + 17408);             // [128][72]
    unsigned short* Pw  = (unsigned short*)(sUN + 35840) + w * (32 * 72); // per-wave [32][72]

    f32x4 O[2][8];
#pragma unroll
    for (int lt = 0; lt < 2; ++lt)
#pragma unroll
        for (int dt = 0; dt < 8; ++dt) O[lt][dt] = (f32x4){0.f, 0.f, 0.f, 0.f};
    float mrow[2][4], lrow[2][4];
#pragma unroll
    for (int lt = 0; lt < 2; ++lt)
#pragma unroll
        for (int r = 0; r < 4; ++r) { mrow[lt][r] = -1e30f; lrow[lt][r] = 0.f; }

    for (int ch = 0; ch < 4; ++ch) {
        const int m0 = ch * 64;
        // build kT-chunk [64][136] and vT-chunk [128][72] (32 tiles, 4 per wave)
        for (int t = w * 4; t < w * 4 + 4; ++t) {
            int mt = t >> 3, dt = t & 7;
            int mr0 = mt * 16;
            bf16x8 a[4];
#pragma unroll
            for (int ks = 0; ks < 4; ++ks)
                a[ks] = *(const bf16x8*)&sPT[(m0 + mr0 + l16) * LDS_STRIDE + ks * 32 + quad * 8];
            f32x4 kacc = {0.f, 0.f, 0.f, 0.f}, vacc = {0.f, 0.f, 0.f, 0.f};
#pragma unroll
            for (int ks = 0; ks < 4; ++ks) {
                bf16x8 bkf = *(const bf16x8*)(Wk_bf + (dt * 16 + l16) * 128 + ks * 32 + quad * 8);
                kacc = __builtin_amdgcn_mfma_f32_16x16x32_bf16(a[ks], bkf, kacc, 0, 0, 0);
                bf16x8 bvf = *(const bf16x8*)(Wv_bf + (dt * 16 + l16) * 128 + ks * 32 + quad * 8);
                vacc = __builtin_amdgcn_mfma_f32_16x16x32_bf16(a[ks], bvf, vacc, 0, 0, 0);
            }
            int d = dt * 16 + l16;
            float kb = bk[d], vb = bv[d];
#pragma unroll
            for (int r = 0; r < 4; ++r)
                kTc[(mr0 + quad * 4 + r) * LDS_STRIDE + d] = f2b(kacc[r] + kb);
            unsigned short vp[4];
#pragma unroll
            for (int r = 0; r < 4; ++r) vp[r] = f2b(vacc[r] + vb);
            unsigned long long pk = (unsigned long long)vp[0]
                                  | ((unsigned long long)vp[1] << 16)
                                  | ((unsigned long long)vp[2] << 32)
                                  | ((unsigned long long)vp[3] << 48);
            *(unsigned long long*)&vTc[d * 72 + mr0 + quad * 4] = pk;
        }
        __syncthreads();

        // S = q . kT^T, online softmax, P -> LDS, O += P . v
#pragma unroll
        for (int lt = 0; lt < 2; ++lt) {
            f32x4 s[4];
#pragma unroll
            for (int nt = 0; nt < 4; ++nt) {
                f32x4 acc = {0.f, 0.f, 0.f, 0.f};
#pragma unroll
                for (int ks = 0; ks < 4; ++ks) {
                    bf16x8 bb = *(const bf16x8*)&kTc[(nt * 16 + l16) * LDS_STRIDE + ks * 32 + quad * 8];
                    acc = __builtin_amdgcn_mfma_f32_16x16x32_bf16(qfrag[lt][ks], bb, acc, 0, 0, 0);
                }
                s[nt] = acc;
            }
#pragma unroll
            for (int r = 0; r < 4; ++r) {
                float mx = fmaxf(fmaxf(s[0][r], s[1][r]), fmaxf(s[2][r], s[3][r]));
#pragma unroll
                for (int off = 8; off; off >>= 1) mx = fmaxf(mx, __shfl_xor(mx, off));
                float mnew  = fmaxf(mrow[lt][r], mx);
                float alpha = __expf(mrow[lt][r] - mnew);
                mrow[lt][r] = mnew;
                float rs = 0.f;
#pragma unroll
                for (int nt = 0; nt < 4; ++nt) {
                    float p = __expf(s[nt][r] - mnew);
                    s[nt][r] = p;
                    rs += p;
                }
#pragma unroll
                for (int off = 8; off; off >>= 1) rs += __shfl_xor(rs, off);
                lrow[lt][r] = lrow[lt][r] * alpha + rs;
#pragma unroll
                for (int dt = 0; dt < 8; ++dt) O[lt][dt][r] *= alpha;
            }
#pragma unroll
            for (int nt = 0; nt < 4; ++nt)
#pragma unroll
                for (int r = 0; r < 4; ++r)
                    Pw[(lt * 16 + quad * 4 + r) * 72 + nt * 16 + l16] = f2b(s[nt][r]);
#pragma unroll
            for (int dt = 0; dt < 8; ++dt) {
                f32x4 acc = O[lt][dt];
#pragma unroll
                for (int kt = 0; kt < 2; ++kt) {
                    bf16x8 pa = *(const bf16x8*)&Pw[(lt * 16 + l16) * 72 + kt * 32 + quad * 8];
                    bf16x8 vb = *(const bf16x8*)&vTc[(dt * 16 + l16) * 72 + kt * 32 + quad * 8];
                    acc = __builtin_amdgcn_mfma_f32_16x16x32_bf16(pa, vb, acc, 0, 0, 0);
                }
                O[lt][dt] = acc;
            }
        }
        __syncthreads();   // protect kTc/vTc overwrite next chunk (and yA reuse after)
    }

    // ---------------- Phase 3: normalize, O-projection, residual, store ------
    unsigned short* yA = (unsigned short*)sUN;   // [256][136] (flash region is dead)
#pragma unroll
    for (int lt = 0; lt < 2; ++lt) {
        float inv[4];
#pragma unroll
        for (int r = 0; r < 4; ++r) inv[r] = 1.f / lrow[lt][r];
#pragma unroll
        for (int dt = 0; dt < 8; ++dt)
#pragma unroll
            for (int r = 0; r < 4; ++r)
                yA[(lbase + lt * 16 + quad * 4 + r) * LDS_STRIDE + dt * 16 + l16] =
                    f2b(O[lt][dt][r] * inv[r]);
    }
    // each wave reads only its own rows -> no barrier needed
#pragma unroll
    for (int lt = 0; lt < 2; ++lt) {
        int l0 = lbase + lt * 16;
        bf16x8 a[4];
#pragma unroll
        for (int ks = 0; ks < 4; ++ks)
            a[ks] = *(const bf16x8*)&yA[(l0 + l16) * LDS_STRIDE + ks * 32 + quad * 8];
#pragma unroll
        for (int ct = 0; ct < 8; ++ct) {
            f32x4 acc = {0.f, 0.f, 0.f, 0.f};
#pragma unroll
            for (int ks = 0; ks < 4; ++ks) {
                bf16x8 bb = *(const bf16x8*)(Wo_bf + (ct * 16 + l16) * 128 + ks * 32 + quad * 8);
                acc = __builtin_amdgcn_mfma_f32_16x16x32_bf16(a[ks], bb, acc, 0, 0, 0);
            }
            int c = ct * 16 + l16;
            float bias = bo[c];
            float* outc = out + patch_off + (long)c * 262144;
#pragma unroll
            for (int r = 0; r < 4; ++r) {
                int l = l0 + quad * 4 + r;
                float res = b2f(sPT[l * LDS_STRIDE + c]);
                int sh = l >> 4, sw = l & 15;
                outc[sh * 512 + sw] = acc[r] + bias + res;
            }
        }
    }
}

extern "C" void kernel_launch(void* const* d_in, const int* in_sizes, int n_in,
                              void* d_out, int out_size, void* d_ws, size_t ws_size,
                              hipStream_t stream) {
    (void)in_sizes; (void)n_in; (void)out_size; (void)ws_size;
    const float* x  = (const float*)d_in[0];
    const float* Wq = (const float*)d_in[1];
    const float* bq = (const float*)d_in[2];
    const float* Wk = (const float*)d_in[3];
    const float* bk = (const float*)d_in[4];
    const float* Wv = (const float*)d_in[5];
    const float* bv = (const float*)d_in[6];
    const float* Wo = (const float*)d_in[7];
    const float* bo = (const float*)d_in[8];
    unsigned short* wbf = (unsigned short*)d_ws;   // 131,072 B of bf16 weights

    prep_weights<<<64, 256, 0, stream>>>(Wq, Wk, Wv, Wo, wbf);
    patch_attn<<<2048, 512, 0, stream>>>(x, bq, bk, bv, bo, wbf, (float*)d_out);
}